// Round 2
// baseline (603.289 us; speedup 1.0000x reference)
//
#include <hip/hip_runtime.h>
#include <math.h>

#define N_NODES 50000
#define N_EDGES 800000
#define N_FEAT 100
#define N_CLASSES 40

// ---------------- edge dtype detection / conversion ----------------

__global__ void k_flag_init(int* flag) { *flag = 1; }  // 1 = int64

// Read first N_EDGES slots as int64 (6.4MB: in-bounds for both int32 and int64
// buffers). If the buffer is int32, each int64 slot packs two node ids
// (lo + hi<<32) and hi is nonzero with p~1 per slot -> value >= N_NODES.
__global__ void k_detect(const long long* __restrict__ ei64, int* flag) {
    int e = blockIdx.x * blockDim.x + threadIdx.x;
    if (e >= N_EDGES) return;
    long long v = ei64[e];
    if (v < 0 || v >= N_NODES) *flag = 0;  // all writers write 0: race-free
}

__global__ void k_convert(const void* __restrict__ ei, const int* __restrict__ flag,
                          int* __restrict__ row32, int* __restrict__ col32) {
    int e = blockIdx.x * blockDim.x + threadIdx.x;
    if (e >= N_EDGES) return;
    if (*flag) {
        const long long* p = (const long long*)ei;
        row32[e] = (int)p[e];
        col32[e] = (int)p[N_EDGES + e];
    } else {
        const int* p = (const int*)ei;
        row32[e] = p[e];
        col32[e] = p[N_EDGES + e];
    }
}

// ---------------- degree / norm ----------------

__global__ void k_deg_init(float* __restrict__ deg, int n) {
    int i = blockIdx.x * blockDim.x + threadIdx.x;
    if (i < n) deg[i] = 1.0f;  // self-loop contributes 1 to every node
}

__global__ void k_deg_count(const int* __restrict__ col, float* __restrict__ deg, int e) {
    int i = blockIdx.x * blockDim.x + threadIdx.x;
    if (i < e) atomicAdd(&deg[col[i]], 1.0f);
}

__global__ void k_dinv(float* __restrict__ deg, int n) {
    int i = blockIdx.x * blockDim.x + threadIdx.x;
    if (i < n) deg[i] = rsqrtf(deg[i]);  // deg >= 1 always
}

__global__ void k_norm(const int* __restrict__ row, const int* __restrict__ col,
                       const float* __restrict__ dinv, float* __restrict__ norm, int e) {
    int i = blockIdx.x * blockDim.x + threadIdx.x;
    if (i < e) norm[i] = dinv[row[i]] * dinv[col[i]];
}

// ---------------- propagation ----------------

// dst[i][f] = dinv[i]^2 * src[i][f]   (self-loop term; also initializes dst)
template <int F>
__global__ void k_selfloop_init(const float* __restrict__ src, const float* __restrict__ dinv,
                                float* __restrict__ dst, int n) {
    int idx = blockIdx.x * blockDim.x + threadIdx.x;
    if (idx >= n * F) return;
    int i = idx / F;
    float d = dinv[i];
    dst[idx] = d * d * src[idx];
}

// dst[col[e]][f] += norm[e] * src[row[e]][f]
template <int F>
__global__ void k_scatter(const int* __restrict__ row, const int* __restrict__ col,
                          const float* __restrict__ norm, const float* __restrict__ src,
                          float* __restrict__ dst, int e) {
    int idx = blockIdx.x * blockDim.x + threadIdx.x;
    if (idx >= e * F) return;  // 80M / 32M: fits int
    int ed = idx / F;
    int f = idx - ed * F;
    int r = row[ed];
    int c = col[ed];
    atomicAdd(&dst[c * F + f], norm[ed] * src[r * F + f]);
}

// ---------------- linear ----------------

__global__ void k_linear(const float* __restrict__ h, const float* __restrict__ W,
                         float* __restrict__ y) {
    __shared__ float Ws[N_FEAT * N_CLASSES];
    for (int i = threadIdx.x; i < N_FEAT * N_CLASSES; i += blockDim.x) Ws[i] = W[i];
    __syncthreads();
    int idx = blockIdx.x * blockDim.x + threadIdx.x;
    if (idx >= N_NODES * N_CLASSES) return;
    int n = idx / N_CLASSES;
    int c = idx - n * N_CLASSES;
    const float* hr = h + n * N_FEAT;
    float s = 0.0f;
#pragma unroll
    for (int k = 0; k < N_FEAT; ++k) s += hr[k] * Ws[k * N_CLASSES + c];
    y[idx] = s;
}

// ---------------- bias + log_softmax (in place on z) ----------------
// one wave per node; 4 nodes per 256-thread block

__global__ void k_logsoftmax(float* __restrict__ z, const float* __restrict__ b) {
    int wave = threadIdx.x >> 6;
    int lane = threadIdx.x & 63;
    int n = blockIdx.x * 4 + wave;
    if (n >= N_NODES) return;
    float v = -INFINITY;
    if (lane < N_CLASSES) v = z[n * N_CLASSES + lane] + b[lane];
    float m = v;
#pragma unroll
    for (int off = 32; off; off >>= 1) m = fmaxf(m, __shfl_xor(m, off));
    float ex = (lane < N_CLASSES) ? __expf(v - m) : 0.0f;
    float s = ex;
#pragma unroll
    for (int off = 32; off; off >>= 1) s += __shfl_xor(s, off);
    float ls = logf(s);
    if (lane < N_CLASSES) z[n * N_CLASSES + lane] = v - m - ls;
}

// ---------------- launch ----------------

extern "C" void kernel_launch(void* const* d_in, const int* in_sizes, int n_in,
                              void* d_out, int out_size, void* d_ws, size_t ws_size,
                              hipStream_t stream) {
    const float* x = (const float*)d_in[0];
    const void* ei = d_in[1];                // [2, E], int32 or int64 (auto-detected)
    const float* W = (const float*)d_in[2];  // [F, C]
    const float* b = (const float*)d_in[3];  // [C]
    float* z = (float*)d_out;                // [N, C]

    // workspace layout
    char* ws = (char*)d_ws;
    int*   flag = (int*)ws;                                  // 4 B (+ pad to 256)
    int*   row  = (int*)(ws + 256);                          // 800000 i32
    int*   col  = (int*)(ws + 256 + 3200000);                // 800000 i32
    float* dinv = (float*)(ws + 256 + 6400000);              // 50000 f
    float* norm = (float*)(ws + 256 + 6400000 + 200192);     // 800000 f
    float* h1   = (float*)(ws + 256 + 6400000 + 200192 + 3200000);             // 50000*100 f
    float* y    = (float*)(ws + 256 + 6400000 + 200192 + 3200000 + 20000000);  // 50000*40 f

    const int T = 256;
    auto blocks = [](long long total, int t) { return (int)((total + t - 1) / t); };

    // edge dtype detect + convert to int32 row/col
    k_flag_init<<<1, 1, 0, stream>>>(flag);
    k_detect<<<blocks(N_EDGES, T), T, 0, stream>>>((const long long*)ei, flag);
    k_convert<<<blocks(N_EDGES, T), T, 0, stream>>>(ei, flag, row, col);

    // degree + normalization
    k_deg_init<<<blocks(N_NODES, T), T, 0, stream>>>(dinv, N_NODES);
    k_deg_count<<<blocks(N_EDGES, T), T, 0, stream>>>(col, dinv, N_EDGES);
    k_dinv<<<blocks(N_NODES, T), T, 0, stream>>>(dinv, N_NODES);
    k_norm<<<blocks(N_EDGES, T), T, 0, stream>>>(row, col, dinv, norm, N_EDGES);

    // hop 1: h1 = A_hat @ x   (F = 100)
    k_selfloop_init<N_FEAT><<<blocks((long long)N_NODES * N_FEAT, T), T, 0, stream>>>(x, dinv, h1, N_NODES);
    k_scatter<N_FEAT><<<blocks((long long)N_EDGES * N_FEAT, T), T, 0, stream>>>(row, col, norm, x, h1, N_EDGES);

    // linear (no bias yet): y = h1 @ W   (commutes with propagation)
    k_linear<<<blocks((long long)N_NODES * N_CLASSES, T), T, 0, stream>>>(h1, W, y);

    // hop 2: z = A_hat @ y    (F = 40), accumulate directly in d_out
    k_selfloop_init<N_CLASSES><<<blocks((long long)N_NODES * N_CLASSES, T), T, 0, stream>>>(y, dinv, z, N_NODES);
    k_scatter<N_CLASSES><<<blocks((long long)N_EDGES * N_CLASSES, T), T, 0, stream>>>(row, col, norm, y, z, N_EDGES);

    // bias + log_softmax in place (4 nodes per block)
    k_logsoftmax<<<(N_NODES + 3) / 4, T, 0, stream>>>(z, b);
}

// Round 3
// 261.146 us; speedup vs baseline: 2.3102x; 2.3102x over previous
//
#include <hip/hip_runtime.h>
#include <math.h>

#define N_NODES 50000
#define N_EDGES 800000
#define N_FEAT 100
#define N_CLASSES 40
#define SCAN_BLK 256
#define N_SCAN_BLKS ((N_NODES + SCAN_BLK - 1) / SCAN_BLK)  // 196

// ---------------- edge dtype detection / conversion ----------------

__global__ void k_flag_init(int* flag) { *flag = 1; }  // 1 = int64

// Read first N_EDGES slots as int64 (6.4MB: in-bounds for both interpretations).
// If buffer is int32, a slot packs two ids and is >= N_NODES with p~1.
__global__ void k_detect(const long long* __restrict__ ei64, int* flag) {
    int e = blockIdx.x * blockDim.x + threadIdx.x;
    if (e >= N_EDGES) return;
    long long v = ei64[e];
    if (v < 0 || v >= N_NODES) *flag = 0;
}

__global__ void k_convert(const void* __restrict__ ei, const int* __restrict__ flag,
                          int* __restrict__ row32, int* __restrict__ col32) {
    int e = blockIdx.x * blockDim.x + threadIdx.x;
    if (e >= N_EDGES) return;
    if (*flag) {
        const long long* p = (const long long*)ei;
        row32[e] = (int)p[e];
        col32[e] = (int)p[N_EDGES + e];
    } else {
        const int* p = (const int*)ei;
        row32[e] = p[e];
        col32[e] = p[N_EDGES + e];
    }
}

// ---------------- degree / dinv ----------------

__global__ void k_zero_deg(int* __restrict__ deg) {
    int i = blockIdx.x * blockDim.x + threadIdx.x;
    if (i < N_NODES) deg[i] = 0;
}

__global__ void k_deg_count(const int* __restrict__ col, int* __restrict__ deg) {
    int i = blockIdx.x * blockDim.x + threadIdx.x;
    if (i < N_EDGES) atomicAdd(&deg[col[i]], 1);
}

__global__ void k_dinv(const int* __restrict__ deg, float* __restrict__ dinv) {
    int i = blockIdx.x * blockDim.x + threadIdx.x;
    if (i < N_NODES) dinv[i] = rsqrtf((float)deg[i] + 1.0f);  // +1 self-loop
}

// ---------------- exclusive scan of deg -> offs (3-kernel) ----------------

__global__ void k_scan1(const int* __restrict__ deg, int* __restrict__ offs,
                        int* __restrict__ sums) {
    __shared__ int s[SCAN_BLK];
    int i = blockIdx.x * SCAN_BLK + threadIdx.x;
    int v = (i < N_NODES) ? deg[i] : 0;
    s[threadIdx.x] = v;
    __syncthreads();
    // Hillis-Steele inclusive scan
    for (int off = 1; off < SCAN_BLK; off <<= 1) {
        int t = (threadIdx.x >= off) ? s[threadIdx.x - off] : 0;
        __syncthreads();
        s[threadIdx.x] += t;
        __syncthreads();
    }
    if (i < N_NODES) offs[i] = s[threadIdx.x] - v;  // exclusive
    if (threadIdx.x == SCAN_BLK - 1) sums[blockIdx.x] = s[SCAN_BLK - 1];
}

__global__ void k_scan2(int* __restrict__ sums) {
    __shared__ int s[SCAN_BLK];
    int v = (threadIdx.x < N_SCAN_BLKS) ? sums[threadIdx.x] : 0;
    s[threadIdx.x] = v;
    __syncthreads();
    for (int off = 1; off < SCAN_BLK; off <<= 1) {
        int t = (threadIdx.x >= off) ? s[threadIdx.x - off] : 0;
        __syncthreads();
        s[threadIdx.x] += t;
        __syncthreads();
    }
    if (threadIdx.x < N_SCAN_BLKS) sums[threadIdx.x] = s[threadIdx.x] - v;  // exclusive
}

__global__ void k_scan3(int* __restrict__ offs, const int* __restrict__ sums,
                        int* __restrict__ cursor) {
    int i = blockIdx.x * SCAN_BLK + threadIdx.x;
    if (i < N_NODES) {
        int o = offs[i] + sums[blockIdx.x];
        offs[i] = o;
        cursor[i] = o;
    }
    if (i == 0) offs[N_NODES] = N_EDGES;
}

// ---------------- CSR fill (by destination) ----------------

__global__ void k_fill(const int* __restrict__ row, const int* __restrict__ col,
                       const float* __restrict__ dinv, int* __restrict__ cursor,
                       int* __restrict__ csr_src, float* __restrict__ csr_norm) {
    int e = blockIdx.x * blockDim.x + threadIdx.x;
    if (e >= N_EDGES) return;
    int r = row[e], c = col[e];
    int pos = atomicAdd(&cursor[c], 1);
    csr_src[pos] = r;
    csr_norm[pos] = dinv[r] * dinv[c];
}

// ---------------- linear: y0 = x @ W (bias deferred) ----------------

__global__ void k_linear(const float* __restrict__ h, const float* __restrict__ W,
                         float* __restrict__ y) {
    __shared__ float Ws[N_FEAT * N_CLASSES];
    for (int i = threadIdx.x; i < N_FEAT * N_CLASSES; i += blockDim.x) Ws[i] = W[i];
    __syncthreads();
    int idx = blockIdx.x * blockDim.x + threadIdx.x;
    if (idx >= N_NODES * N_CLASSES) return;
    int n = idx / N_CLASSES;
    int c = idx - n * N_CLASSES;
    const float* hr = h + n * N_FEAT;
    float s = 0.0f;
#pragma unroll
    for (int k = 0; k < N_FEAT; ++k) s += hr[k] * Ws[k * N_CLASSES + c];
    y[idx] = s;
}

// ---------------- pull-gather hop: dst[n] = dinv[n]^2 src[n] + sum norm*src[r] ----------------
// one wave per node (lanes 0..39 = features), 4 nodes per 256-thread block

template <int F>
__global__ void k_gather(const int* __restrict__ offs, const int* __restrict__ csr_src,
                         const float* __restrict__ csr_norm, const float* __restrict__ src,
                         const float* __restrict__ dinv, float* __restrict__ dst) {
    int wave = threadIdx.x >> 6;
    int lane = threadIdx.x & 63;
    int n = blockIdx.x * 4 + wave;
    if (n >= N_NODES || lane >= F) return;
    float d = dinv[n];
    float acc = d * d * src[n * F + lane];
    int s = offs[n], e = offs[n + 1];
    int i = s;
    for (; i + 1 < e; i += 2) {
        int r0 = csr_src[i], r1 = csr_src[i + 1];
        float w0 = csr_norm[i], w1 = csr_norm[i + 1];
        acc += w0 * src[r0 * F + lane];
        acc += w1 * src[r1 * F + lane];
    }
    if (i < e) {
        int r0 = csr_src[i];
        acc += csr_norm[i] * src[r0 * F + lane];
    }
    dst[n * F + lane] = acc;
}

// ---------------- bias + log_softmax (in place on z) ----------------

__global__ void k_logsoftmax(float* __restrict__ z, const float* __restrict__ b) {
    int wave = threadIdx.x >> 6;
    int lane = threadIdx.x & 63;
    int n = blockIdx.x * 4 + wave;
    if (n >= N_NODES) return;
    float v = -INFINITY;
    if (lane < N_CLASSES) v = z[n * N_CLASSES + lane] + b[lane];
    float m = v;
#pragma unroll
    for (int off = 32; off; off >>= 1) m = fmaxf(m, __shfl_xor(m, off));
    float ex = (lane < N_CLASSES) ? __expf(v - m) : 0.0f;
    float s = ex;
#pragma unroll
    for (int off = 32; off; off >>= 1) s += __shfl_xor(s, off);
    float ls = logf(s);
    if (lane < N_CLASSES) z[n * N_CLASSES + lane] = v - m - ls;
}

// ---------------- launch ----------------

extern "C" void kernel_launch(void* const* d_in, const int* in_sizes, int n_in,
                              void* d_out, int out_size, void* d_ws, size_t ws_size,
                              hipStream_t stream) {
    const float* x = (const float*)d_in[0];
    const void* ei = d_in[1];                // [2, E], int32 or int64 (auto-detected)
    const float* W = (const float*)d_in[2];  // [F, C]
    const float* b = (const float*)d_in[3];  // [C]
    float* z = (float*)d_out;                // [N, C]

    // workspace layout (all offsets 256B-aligned)
    char* ws = (char*)d_ws;
    size_t o = 0;
    auto alloc = [&](size_t bytes) { char* p = ws + o; o += (bytes + 255) & ~(size_t)255; return p; };
    int*   flag     = (int*)alloc(4);
    int*   row      = (int*)alloc(N_EDGES * 4);
    int*   col      = (int*)alloc(N_EDGES * 4);
    int*   deg      = (int*)alloc(N_NODES * 4);
    float* dinv     = (float*)alloc(N_NODES * 4);
    int*   offs     = (int*)alloc((N_NODES + 1) * 4);
    int*   cursor   = (int*)alloc(N_NODES * 4);
    int*   sums     = (int*)alloc(SCAN_BLK * 4);
    int*   csr_src  = (int*)alloc(N_EDGES * 4);
    float* csr_norm = (float*)alloc(N_EDGES * 4);
    float* y0       = (float*)alloc((size_t)N_NODES * N_CLASSES * 4);
    float* h1       = (float*)alloc((size_t)N_NODES * N_CLASSES * 4);

    const int T = 256;
    auto blocks = [](long long total, int t) { return (int)((total + t - 1) / t); };

    // edge dtype detect + convert
    k_flag_init<<<1, 1, 0, stream>>>(flag);
    k_detect<<<blocks(N_EDGES, T), T, 0, stream>>>((const long long*)ei, flag);
    k_convert<<<blocks(N_EDGES, T), T, 0, stream>>>(ei, flag, row, col);

    // degrees + dinv
    k_zero_deg<<<blocks(N_NODES, T), T, 0, stream>>>(deg);
    k_deg_count<<<blocks(N_EDGES, T), T, 0, stream>>>(col, deg);
    k_dinv<<<blocks(N_NODES, T), T, 0, stream>>>(deg, dinv);

    // exclusive scan -> offs, cursor
    k_scan1<<<N_SCAN_BLKS, SCAN_BLK, 0, stream>>>(deg, offs, sums);
    k_scan2<<<1, SCAN_BLK, 0, stream>>>(sums);
    k_scan3<<<N_SCAN_BLKS, SCAN_BLK, 0, stream>>>(offs, sums, cursor);

    // CSR fill
    k_fill<<<blocks(N_EDGES, T), T, 0, stream>>>(row, col, dinv, cursor, csr_src, csr_norm);

    // y0 = x @ W  (W commutes with propagation; both hops now F=40)
    k_linear<<<blocks((long long)N_NODES * N_CLASSES, T), T, 0, stream>>>(x, W, y0);

    // hop 1: h1 = A_hat @ y0
    k_gather<N_CLASSES><<<(N_NODES + 3) / 4, T, 0, stream>>>(offs, csr_src, csr_norm, y0, dinv, h1);
    // hop 2: z = A_hat @ h1
    k_gather<N_CLASSES><<<(N_NODES + 3) / 4, T, 0, stream>>>(offs, csr_src, csr_norm, h1, dinv, z);

    // bias + log_softmax in place
    k_logsoftmax<<<(N_NODES + 3) / 4, T, 0, stream>>>(z, b);
}

// Round 4
// 201.928 us; speedup vs baseline: 2.9876x; 1.2933x over previous
//
#include <hip/hip_runtime.h>
#include <math.h>

#define N_NODES 50000
#define N_EDGES 800000
#define N_FEAT 100
#define N_CLASSES 40
#define SCAN_BLK 256
#define N_SCAN_BLKS ((N_NODES + SCAN_BLK - 1) / SCAN_BLK)  // 196

// ---------------- edge dtype detection / conversion ----------------

__global__ void k_flag_init(int* flag) { *flag = 1; }  // 1 = int64

// Read first N_EDGES slots as int64 (6.4MB: exactly the int32 buffer size,
// in-bounds either way). If buffer is int32, a slot packs two ids and is
// >= N_NODES with p~1.
__global__ void k_detect(const long long* __restrict__ ei64, int* flag) {
    int e = blockIdx.x * blockDim.x + threadIdx.x;
    if (e >= N_EDGES) return;
    long long v = ei64[e];
    if (v < 0 || v >= N_NODES) *flag = 0;
}

// pack (r, c) -> r | c<<16  (both < 65536)
__global__ void k_convert(const void* __restrict__ ei, const int* __restrict__ flag,
                          unsigned int* __restrict__ epack) {
    int e = blockIdx.x * blockDim.x + threadIdx.x;
    if (e >= N_EDGES) return;
    unsigned int r, c;
    if (*flag) {
        const long long* p = (const long long*)ei;
        r = (unsigned int)p[e];
        c = (unsigned int)p[N_EDGES + e];
    } else {
        const unsigned int* p = (const unsigned int*)ei;
        r = p[e];
        c = p[N_EDGES + e];
    }
    epack[e] = r | (c << 16);
}

// ---------------- degree ----------------

__global__ void k_deg_count(const unsigned int* __restrict__ epack, int* __restrict__ deg) {
    int i = blockIdx.x * blockDim.x + threadIdx.x;
    if (i < N_EDGES) atomicAdd(&deg[epack[i] >> 16], 1);
}

// ---------------- exclusive scan of deg -> offs (+ dinv fused) ----------------

__global__ void k_scan1(const int* __restrict__ deg, int* __restrict__ offs,
                        int* __restrict__ sums, float* __restrict__ dinv) {
    __shared__ int s[SCAN_BLK];
    int i = blockIdx.x * SCAN_BLK + threadIdx.x;
    int v = (i < N_NODES) ? deg[i] : 0;
    if (i < N_NODES) dinv[i] = rsqrtf((float)v + 1.0f);  // +1 self-loop
    s[threadIdx.x] = v;
    __syncthreads();
    for (int off = 1; off < SCAN_BLK; off <<= 1) {
        int t = (threadIdx.x >= off) ? s[threadIdx.x - off] : 0;
        __syncthreads();
        s[threadIdx.x] += t;
        __syncthreads();
    }
    if (i < N_NODES) offs[i] = s[threadIdx.x] - v;  // exclusive
    if (threadIdx.x == SCAN_BLK - 1) sums[blockIdx.x] = s[SCAN_BLK - 1];
}

__global__ void k_scan2(int* __restrict__ sums) {
    __shared__ int s[SCAN_BLK];
    int v = (threadIdx.x < N_SCAN_BLKS) ? sums[threadIdx.x] : 0;
    s[threadIdx.x] = v;
    __syncthreads();
    for (int off = 1; off < SCAN_BLK; off <<= 1) {
        int t = (threadIdx.x >= off) ? s[threadIdx.x - off] : 0;
        __syncthreads();
        s[threadIdx.x] += t;
        __syncthreads();
    }
    if (threadIdx.x < N_SCAN_BLKS) sums[threadIdx.x] = s[threadIdx.x] - v;  // exclusive
}

__global__ void k_scan3(int* __restrict__ offs, const int* __restrict__ sums,
                        int* __restrict__ cursor) {
    int i = blockIdx.x * SCAN_BLK + threadIdx.x;
    if (i < N_NODES) {
        int o = offs[i] + sums[blockIdx.x];
        offs[i] = o;
        cursor[i] = o;
    }
    if (i == 0) offs[N_NODES] = N_EDGES;
}

// ---------------- CSR fill: one 8B entry (src, norm) per edge ----------------

__global__ void k_fill(const unsigned int* __restrict__ epack, const float* __restrict__ dinv,
                       int* __restrict__ cursor, uint2* __restrict__ csr) {
    int e = blockIdx.x * blockDim.x + threadIdx.x;
    if (e >= N_EDGES) return;
    unsigned int p = epack[e];
    unsigned int r = p & 0xffffu, c = p >> 16;
    int pos = atomicAdd(&cursor[c], 1);
    float w = dinv[r] * dinv[c];
    csr[pos] = make_uint2(r, __float_as_uint(w));
}

// ---------------- linear: y0 = x @ W (bias deferred) ----------------
// thread = (node, class-quad); W transposed in LDS for broadcast reads

__global__ void k_linear(const float* __restrict__ h, const float* __restrict__ W,
                         float* __restrict__ y) {
    __shared__ float4 Ws[N_CLASSES / 4][N_FEAT];  // [c4][k], 16 KB
    for (int i = threadIdx.x; i < N_FEAT * (N_CLASSES / 4); i += blockDim.x) {
        int k = i / (N_CLASSES / 4), c4 = i - k * (N_CLASSES / 4);
        Ws[c4][k] = ((const float4*)W)[i];
    }
    __syncthreads();
    int idx = blockIdx.x * blockDim.x + threadIdx.x;
    if (idx >= N_NODES * (N_CLASSES / 4)) return;
    int n = idx / (N_CLASSES / 4);
    int c4 = idx - n * (N_CLASSES / 4);
    const float* hr = h + n * N_FEAT;
    float4 s = {0.f, 0.f, 0.f, 0.f};
#pragma unroll
    for (int k = 0; k < N_FEAT; ++k) {
        float hv = hr[k];
        float4 w = Ws[c4][k];
        s.x += hv * w.x; s.y += hv * w.y; s.z += hv * w.z; s.w += hv * w.w;
    }
    ((float4*)y)[idx] = s;
}

// ---------------- pull-gather hop (optionally fused bias+log_softmax) ----------------
// one wave per node (lanes 0..39 = classes), 4 nodes per 256-thread block

template <int F, bool LSM>
__global__ void k_gather(const int* __restrict__ offs, const uint2* __restrict__ csr,
                         const float* __restrict__ src, const float* __restrict__ dinv,
                         float* __restrict__ dst, const float* __restrict__ bias) {
    int wave = threadIdx.x >> 6;
    int lane = threadIdx.x & 63;
    int n = blockIdx.x * 4 + wave;
    if (n >= N_NODES) return;
    int s = offs[n], e = offs[n + 1];
    float acc = 0.0f;
    if (lane < F) {
        float d = dinv[n];
        acc = d * d * src[n * F + lane];
    }
    int i = s;
    for (; i + 3 < e; i += 4) {
        uint2 e0 = csr[i], e1 = csr[i + 1], e2 = csr[i + 2], e3 = csr[i + 3];
        if (lane < F) {
            acc += __uint_as_float(e0.y) * src[e0.x * F + lane];
            acc += __uint_as_float(e1.y) * src[e1.x * F + lane];
            acc += __uint_as_float(e2.y) * src[e2.x * F + lane];
            acc += __uint_as_float(e3.y) * src[e3.x * F + lane];
        }
    }
    for (; i < e; ++i) {
        uint2 e0 = csr[i];
        if (lane < F) acc += __uint_as_float(e0.y) * src[e0.x * F + lane];
    }
    if (!LSM) {
        if (lane < F) dst[n * F + lane] = acc;
    } else {
        float v = (lane < F) ? acc + bias[lane] : -INFINITY;
        float m = v;
#pragma unroll
        for (int off = 32; off; off >>= 1) m = fmaxf(m, __shfl_xor(m, off));
        float ex = (lane < F) ? __expf(v - m) : 0.0f;
        float ssum = ex;
#pragma unroll
        for (int off = 32; off; off >>= 1) ssum += __shfl_xor(ssum, off);
        float ls = logf(ssum);
        if (lane < F) dst[n * F + lane] = v - m - ls;
    }
}

// ---------------- launch ----------------

extern "C" void kernel_launch(void* const* d_in, const int* in_sizes, int n_in,
                              void* d_out, int out_size, void* d_ws, size_t ws_size,
                              hipStream_t stream) {
    const float* x = (const float*)d_in[0];
    const void* ei = d_in[1];                // [2, E], int32 or int64 (auto-detected)
    const float* W = (const float*)d_in[2];  // [F, C]
    const float* b = (const float*)d_in[3];  // [C]
    float* z = (float*)d_out;                // [N, C]

    // workspace layout (256B-aligned chunks)
    char* ws = (char*)d_ws;
    size_t o = 0;
    auto alloc = [&](size_t bytes) { char* p = ws + o; o += (bytes + 255) & ~(size_t)255; return p; };
    int*          flag   = (int*)alloc(4);
    unsigned int* epack  = (unsigned int*)alloc((size_t)N_EDGES * 4);
    int*          deg    = (int*)alloc(N_NODES * 4);
    float*        dinv   = (float*)alloc(N_NODES * 4);
    int*          offs   = (int*)alloc((N_NODES + 1) * 4);
    int*          cursor = (int*)alloc(N_NODES * 4);
    int*          sums   = (int*)alloc(SCAN_BLK * 4);
    uint2*        csr    = (uint2*)alloc((size_t)N_EDGES * 8);
    float*        y0     = (float*)alloc((size_t)N_NODES * N_CLASSES * 4);
    float*        h1     = (float*)alloc((size_t)N_NODES * N_CLASSES * 4);

    const int T = 256;
    auto blocks = [](long long total, int t) { return (int)((total + t - 1) / t); };

    // edge dtype detect + convert to packed u32
    k_flag_init<<<1, 1, 0, stream>>>(flag);
    k_detect<<<blocks(N_EDGES, T), T, 0, stream>>>((const long long*)ei, flag);
    k_convert<<<blocks(N_EDGES, T), T, 0, stream>>>(ei, flag, epack);

    // degrees
    hipMemsetAsync(deg, 0, N_NODES * 4, stream);
    k_deg_count<<<blocks(N_EDGES, T), T, 0, stream>>>(epack, deg);

    // exclusive scan -> offs, cursor (dinv fused into scan1)
    k_scan1<<<N_SCAN_BLKS, SCAN_BLK, 0, stream>>>(deg, offs, sums, dinv);
    k_scan2<<<1, SCAN_BLK, 0, stream>>>(sums);
    k_scan3<<<N_SCAN_BLKS, SCAN_BLK, 0, stream>>>(offs, sums, cursor);

    // CSR fill (one 8B interleaved entry per edge)
    k_fill<<<blocks(N_EDGES, T), T, 0, stream>>>(epack, dinv, cursor, csr);

    // y0 = x @ W  (W commutes with propagation; both hops F=40)
    k_linear<<<blocks((long long)N_NODES * (N_CLASSES / 4), T), T, 0, stream>>>(x, W, y0);

    // hop 1: h1 = A_hat @ y0
    k_gather<N_CLASSES, false><<<(N_NODES + 3) / 4, T, 0, stream>>>(offs, csr, y0, dinv, h1, b);
    // hop 2 fused with bias + log_softmax: z = log_softmax(A_hat @ h1 + b)
    k_gather<N_CLASSES, true><<<(N_NODES + 3) / 4, T, 0, stream>>>(offs, csr, h1, dinv, z, b);
}